// Round 1
// baseline (605.538 us; speedup 1.0000x reference)
//
#include <hip/hip_runtime.h>
#include <math.h>

#define NN 100000
#define EE 1600000
#define IND 128
#define D64 64   // HEADS*OUT_DIM

// ---------------------------------------------------------------------------
// Kernel 1: fused Q/K/V projection. 192 threads = 3 waves (Q, K, V).
// Each block handles 16 nodes; each thread owns one output column, 16 nodes.
// x reads are wave-uniform (scalar path); W reads coalesced across lanes.
// ---------------------------------------------------------------------------
__global__ __launch_bounds__(192) void qkv_kernel(
    const float* __restrict__ x,
    const float* __restrict__ Wq, const float* __restrict__ bq,
    const float* __restrict__ Wk, const float* __restrict__ bk,
    const float* __restrict__ Wv, const float* __restrict__ bv,
    float* __restrict__ Qo, float* __restrict__ Ko, float* __restrict__ Vo)
{
    const int wave = threadIdx.x >> 6;
    const int lane = threadIdx.x & 63;
    const int nodeBase = blockIdx.x * 16;

    const float* W; const float* b; float* O;
    if (wave == 0)      { W = Wq; b = bq; O = Qo; }
    else if (wave == 1) { W = Wk; b = bk; O = Ko; }
    else                { W = Wv; b = bv; O = Vo; }

    float acc[16];
#pragma unroll
    for (int n = 0; n < 16; ++n) acc[n] = 0.f;

    const float* xb = x + (size_t)nodeBase * IND;

#pragma unroll 2
    for (int kt = 0; kt < 8; ++kt) {
        float wr[16];
#pragma unroll
        for (int j = 0; j < 16; ++j) wr[j] = W[(kt*16 + j)*D64 + lane];
#pragma unroll
        for (int n = 0; n < 16; ++n) {
            const float4* xp = (const float4*)(xb + n*IND + kt*16);
            float4 a0 = xp[0];
            float4 a1 = xp[1];
            float4 a2 = xp[2];
            float4 a3 = xp[3];
            float s = acc[n];
            s = fmaf(a0.x, wr[0],  s); s = fmaf(a0.y, wr[1],  s);
            s = fmaf(a0.z, wr[2],  s); s = fmaf(a0.w, wr[3],  s);
            s = fmaf(a1.x, wr[4],  s); s = fmaf(a1.y, wr[5],  s);
            s = fmaf(a1.z, wr[6],  s); s = fmaf(a1.w, wr[7],  s);
            s = fmaf(a2.x, wr[8],  s); s = fmaf(a2.y, wr[9],  s);
            s = fmaf(a2.z, wr[10], s); s = fmaf(a2.w, wr[11], s);
            s = fmaf(a3.x, wr[12], s); s = fmaf(a3.y, wr[13], s);
            s = fmaf(a3.z, wr[14], s); s = fmaf(a3.w, wr[15], s);
            acc[n] = s;
        }
    }

    const float bias = b[lane];
#pragma unroll
    for (int n = 0; n < 16; ++n)
        O[(size_t)(nodeBase + n) * D64 + lane] = acc[n] + bias;
}

// ---------------------------------------------------------------------------
// Kernel 2: degree count by destination node.
// ---------------------------------------------------------------------------
__global__ __launch_bounds__(256) void count_kernel(const int* __restrict__ ei,
                                                    int* __restrict__ deg)
{
    int e = blockIdx.x * blockDim.x + threadIdx.x;
    if (e < EE) atomicAdd(&deg[ei[EE + e]], 1);
}

// ---------------------------------------------------------------------------
// Exclusive prefix-sum over deg[0..NN-1] (+ virtual 0 at index NN) -> off[0..NN]
// 3-kernel scan: per-block sums -> scan sums -> final scan + write cursor copy.
// Each scan block covers 1024 elements (256 thr x 4).
// ---------------------------------------------------------------------------
__global__ __launch_bounds__(256) void scanA_kernel(const int* __restrict__ deg,
                                                    int* __restrict__ bsums)
{
    int base = blockIdx.x * 1024 + threadIdx.x * 4;
    int s = 0;
#pragma unroll
    for (int j = 0; j < 4; ++j) {
        int i = base + j;
        s += (i < NN) ? deg[i] : 0;
    }
    for (int o = 32; o > 0; o >>= 1) s += __shfl_xor(s, o);
    __shared__ int ws[4];
    if ((threadIdx.x & 63) == 0) ws[threadIdx.x >> 6] = s;
    __syncthreads();
    if (threadIdx.x == 0) bsums[blockIdx.x] = ws[0] + ws[1] + ws[2] + ws[3];
}

__global__ __launch_bounds__(128) void scanB_kernel(int* __restrict__ bsums, int nb)
{
    __shared__ int sh[128];
    int t = threadIdx.x;
    int v = (t < nb) ? bsums[t] : 0;
    sh[t] = v;
    __syncthreads();
    for (int o = 1; o < 128; o <<= 1) {
        int add = (t >= o) ? sh[t - o] : 0;
        __syncthreads();
        sh[t] += add;
        __syncthreads();
    }
    if (t < nb) bsums[t] = sh[t] - v;   // exclusive
}

__global__ __launch_bounds__(256) void scanC_kernel(const int* __restrict__ deg,
                                                    const int* __restrict__ bsums,
                                                    int* __restrict__ off,
                                                    int* __restrict__ cursor)
{
    int t = threadIdx.x;
    int base = blockIdx.x * 1024 + t * 4;
    int L[4]; int s = 0;
#pragma unroll
    for (int j = 0; j < 4; ++j) {
        int i = base + j;
        L[j] = (i < NN) ? deg[i] : 0;
        s += L[j];
    }
    int lane = t & 63, w = t >> 6;
    int incl = s;
    for (int o = 1; o < 64; o <<= 1) {
        int v = __shfl_up(incl, o);
        if (lane >= o) incl += v;
    }
    __shared__ int wsum[4];
    if (lane == 63) wsum[w] = incl;
    __syncthreads();
    int wbase = 0;
#pragma unroll
    for (int i = 0; i < 4; ++i) if (i < w) wbase += wsum[i];
    int run = bsums[blockIdx.x] + wbase + incl - s;
#pragma unroll
    for (int j = 0; j < 4; ++j) {
        int i = base + j;
        if (i <= NN) off[i] = run;
        if (i < NN)  cursor[i] = run;
        run += L[j];
    }
}

// ---------------------------------------------------------------------------
// Kernel: scatter edges into CSR slots (src id + edge_attr), by dst.
// ---------------------------------------------------------------------------
__global__ __launch_bounds__(256) void scatter_kernel(const int* __restrict__ ei,
                                                      const float* __restrict__ ea,
                                                      int* __restrict__ cursor,
                                                      int* __restrict__ esrc,
                                                      float* __restrict__ eattr)
{
    int e = blockIdx.x * blockDim.x + threadIdx.x;
    if (e >= EE) return;
    int d = ei[EE + e];
    int pos = atomicAdd(&cursor[d], 1);
    esrc[pos]  = ei[e];
    eattr[pos] = ea[e];
}

// ---------------------------------------------------------------------------
// Kernel: per-destination-node attention. One wave per node; lane = h*8+d.
// Q hoisted; per-edge K/V gathers are single coalesced 256B loads; 8-lane
// shfl_xor dot; exp(clip) score; register accumulation; fused normalize.
// ---------------------------------------------------------------------------
__global__ __launch_bounds__(256) void attn_kernel(
    const float* __restrict__ Q, const float* __restrict__ K,
    const float* __restrict__ V,
    const int* __restrict__ off, const int* __restrict__ esrc,
    const float* __restrict__ eattr,
    const float* __restrict__ We, const float* __restrict__ be,
    float* __restrict__ out)
{
    const int lane = threadIdx.x & 63;
    const int node = blockIdx.x * 4 + (threadIdx.x >> 6);
    if (node >= NN) return;

    const float we  = We[lane];
    const float beL = be[lane];
    const float q   = Q[node * D64 + lane];

    const int i0 = off[node];
    const int i1 = off[node + 1];

    float acc = 0.f, z = 0.f;
    const float rs = 0.35355339059327373f;  // 1/sqrt(8)

    for (int i = i0; i < i1; ++i) {
        int   s = esrc[i];
        float a = eattr[i];
        float k = K[s * D64 + lane];
        float v = V[s * D64 + lane];
        float eh = fmaf(a, we, beL);
        float t  = k * q * eh;
        t += __shfl_xor(t, 1);
        t += __shfl_xor(t, 2);
        t += __shfl_xor(t, 4);
        t *= rs;
        t = fminf(fmaxf(t, -5.f), 5.f);
        float sc = __expf(t);
        acc = fmaf(v, sc, acc);
        z  += sc;
    }
    out[node * D64 + lane] = acc / (z + 1e-6f);
}

// ---------------------------------------------------------------------------
// Host launcher
// ---------------------------------------------------------------------------
static inline size_t align256(size_t v) { return (v + 255) & ~(size_t)255; }

extern "C" void kernel_launch(void* const* d_in, const int* in_sizes, int n_in,
                              void* d_out, int out_size, void* d_ws, size_t ws_size,
                              hipStream_t stream)
{
    const float* x  = (const float*)d_in[0];
    const float* ea = (const float*)d_in[1];
    const int*   ei = (const int*)  d_in[2];   // [2][EE]: row0=src, row1=dst
    const float* Wq = (const float*)d_in[3];
    const float* bq = (const float*)d_in[4];
    const float* Wk = (const float*)d_in[5];
    const float* bk = (const float*)d_in[6];
    const float* We = (const float*)d_in[7];
    const float* be = (const float*)d_in[8];
    const float* Wv = (const float*)d_in[9];
    const float* bv = (const float*)d_in[10];
    float* out = (float*)d_out;

    char* ws = (char*)d_ws;
    size_t o = 0;
    float* Q      = (float*)(ws + o); o += align256((size_t)NN * D64 * 4);
    float* K      = (float*)(ws + o); o += align256((size_t)NN * D64 * 4);
    float* V      = (float*)(ws + o); o += align256((size_t)NN * D64 * 4);
    int*   deg    = (int*)  (ws + o); o += align256((size_t)NN * 4);
    int*   cursor = (int*)  (ws + o); o += align256((size_t)NN * 4);
    int*   off    = (int*)  (ws + o); o += align256((size_t)(NN + 1) * 4);
    int*   bsums  = (int*)  (ws + o); o += align256(128 * 4);
    int*   esrc   = (int*)  (ws + o); o += align256((size_t)EE * 4);
    float* eattr  = (float*)(ws + o); o += align256((size_t)EE * 4);
    (void)ws_size; (void)out_size; (void)in_sizes; (void)n_in;

    const int nbScan = (NN + 1 + 1023) / 1024;   // 98

    hipMemsetAsync(deg, 0, (size_t)NN * 4, stream);

    qkv_kernel<<<NN / 16, 192, 0, stream>>>(x, Wq, bq, Wk, bk, Wv, bv, Q, K, V);
    count_kernel<<<EE / 256, 256, 0, stream>>>(ei, deg);
    scanA_kernel<<<nbScan, 256, 0, stream>>>(deg, bsums);
    scanB_kernel<<<1, 128, 0, stream>>>(bsums, nbScan);
    scanC_kernel<<<nbScan, 256, 0, stream>>>(deg, bsums, off, cursor);
    scatter_kernel<<<EE / 256, 256, 0, stream>>>(ei, ea, cursor, esrc, eattr);
    attn_kernel<<<NN / 4, 256, 0, stream>>>(Q, K, V, off, esrc, eattr, We, be, out);
}

// Round 2
// 501.802 us; speedup vs baseline: 1.2067x; 1.2067x over previous
//
#include <hip/hip_runtime.h>
#include <math.h>

#define NN 100000
#define EE 1600000
#define IND 128
#define D64 64   // HEADS*OUT_DIM

// ---------------------------------------------------------------------------
// Kernel 1: fused Q/K/V projection as one register-tiled LDS GEMM.
// C[100000 x 192] = x[100000 x 128] @ [Wq|Wk|Wv][128 x 192]
// Block: 256 threads, BM=64 nodes, BN=192 cols, BK=32.
// Thread tile: 8 nodes x 6 cols (cols strided by 32 -> conflict-free LDS
// reads + coalesced output writes). xs reads are wave-broadcast.
// ---------------------------------------------------------------------------
#define XS_STRIDE 36
#define WS_STRIDE 196

__global__ __launch_bounds__(256) void qkv_kernel(
    const float* __restrict__ x,
    const float* __restrict__ Wq, const float* __restrict__ bq,
    const float* __restrict__ Wk, const float* __restrict__ bk,
    const float* __restrict__ Wv, const float* __restrict__ bv,
    float* __restrict__ Qo, float* __restrict__ Ko, float* __restrict__ Vo)
{
    __shared__ float xs[64 * XS_STRIDE];   // [node][k], stride 36 (bank-spread)
    __shared__ float ws[32 * WS_STRIDE];   // [k][col],  stride 196

    const int t    = threadIdx.x;
    const int tidn = t & 31;    // col group: cols j*32 + tidn
    const int tidm = t >> 5;    // node group: nodes tidm*8 .. +8
    const int nb   = blockIdx.x * 64;

    float acc[6][8];
#pragma unroll
    for (int j = 0; j < 6; ++j)
#pragma unroll
        for (int n = 0; n < 8; ++n) acc[j][n] = 0.f;

    const float* const Wm[3] = { Wq, Wk, Wv };

    for (int kt = 0; kt < 4; ++kt) {
        // ---- stage x tile: 64 nodes x 32 k  (2 float4 per thread) ----
#pragma unroll
        for (int i = 0; i < 2; ++i) {
            int idx  = i * 256 + t;          // 0..511
            int node = idx >> 3, k4 = idx & 7;
            float4 v = make_float4(0.f, 0.f, 0.f, 0.f);
            if (nb + node < NN)
                v = *(const float4*)&x[(size_t)(nb + node) * IND + kt * 32 + k4 * 4];
            *(float4*)&xs[node * XS_STRIDE + k4 * 4] = v;
        }
        // ---- stage W chunk: 32 k x 192 cols (6 float4 per thread) ----
#pragma unroll
        for (int m = 0; m < 3; ++m) {
#pragma unroll
            for (int i = 0; i < 2; ++i) {
                int idx = i * 256 + t;       // 0..511
                int k = idx >> 4, c4 = idx & 15;
                float4 v = *(const float4*)&Wm[m][(size_t)(kt * 32 + k) * D64 + c4 * 4];
                *(float4*)&ws[k * WS_STRIDE + m * 64 + c4 * 4] = v;
            }
        }
        __syncthreads();

        // ---- compute: 32 k-steps, 48 FMAs each ----
#pragma unroll
        for (int k4 = 0; k4 < 8; ++k4) {
            float4 xv[8];
#pragma unroll
            for (int n = 0; n < 8; ++n)
                xv[n] = *(const float4*)&xs[(tidm * 8 + n) * XS_STRIDE + k4 * 4];
#pragma unroll
            for (int kk = 0; kk < 4; ++kk) {
                float wv[6];
#pragma unroll
                for (int j = 0; j < 6; ++j)
                    wv[j] = ws[(k4 * 4 + kk) * WS_STRIDE + j * 32 + tidn];
#pragma unroll
                for (int j = 0; j < 6; ++j) {
#pragma unroll
                    for (int n = 0; n < 8; ++n) {
                        float xe = (kk == 0) ? xv[n].x : (kk == 1) ? xv[n].y
                                 : (kk == 2) ? xv[n].z : xv[n].w;
                        acc[j][n] = fmaf(xe, wv[j], acc[j][n]);
                    }
                }
            }
        }
        __syncthreads();
    }

    // ---- epilogue: bias + store (coalesced across tidn) ----
#pragma unroll
    for (int j = 0; j < 6; ++j) {
        int col = j * 32 + tidn;
        int m   = col >> 6, lc = col & 63;
        const float* bp = (m == 0) ? bq : (m == 1) ? bk : bv;
        float*       O  = (m == 0) ? Qo : (m == 1) ? Ko : Vo;
        float bias = bp[lc];
#pragma unroll
        for (int n = 0; n < 8; ++n) {
            int node = nb + tidm * 8 + n;
            if (node < NN)
                O[(size_t)node * D64 + lc] = acc[j][n] + bias;
        }
    }
}

// ---------------------------------------------------------------------------
// Kernel 2: degree count by destination node.
// ---------------------------------------------------------------------------
__global__ __launch_bounds__(256) void count_kernel(const int* __restrict__ ei,
                                                    int* __restrict__ deg)
{
    int e = blockIdx.x * blockDim.x + threadIdx.x;
    if (e < EE) atomicAdd(&deg[ei[EE + e]], 1);
}

// ---------------------------------------------------------------------------
// Exclusive prefix-sum over deg -> off[0..NN]; 3-kernel scan, 1024 elems/block.
// ---------------------------------------------------------------------------
__global__ __launch_bounds__(256) void scanA_kernel(const int* __restrict__ deg,
                                                    int* __restrict__ bsums)
{
    int base = blockIdx.x * 1024 + threadIdx.x * 4;
    int s = 0;
#pragma unroll
    for (int j = 0; j < 4; ++j) {
        int i = base + j;
        s += (i < NN) ? deg[i] : 0;
    }
    for (int o = 32; o > 0; o >>= 1) s += __shfl_xor(s, o);
    __shared__ int ws[4];
    if ((threadIdx.x & 63) == 0) ws[threadIdx.x >> 6] = s;
    __syncthreads();
    if (threadIdx.x == 0) bsums[blockIdx.x] = ws[0] + ws[1] + ws[2] + ws[3];
}

__global__ __launch_bounds__(128) void scanB_kernel(int* __restrict__ bsums, int nb)
{
    __shared__ int sh[128];
    int t = threadIdx.x;
    int v = (t < nb) ? bsums[t] : 0;
    sh[t] = v;
    __syncthreads();
    for (int o = 1; o < 128; o <<= 1) {
        int add = (t >= o) ? sh[t - o] : 0;
        __syncthreads();
        sh[t] += add;
        __syncthreads();
    }
    if (t < nb) bsums[t] = sh[t] - v;   // exclusive
}

__global__ __launch_bounds__(256) void scanC_kernel(const int* __restrict__ deg,
                                                    const int* __restrict__ bsums,
                                                    int* __restrict__ off,
                                                    int* __restrict__ cursor)
{
    int t = threadIdx.x;
    int base = blockIdx.x * 1024 + t * 4;
    int L[4]; int s = 0;
#pragma unroll
    for (int j = 0; j < 4; ++j) {
        int i = base + j;
        L[j] = (i < NN) ? deg[i] : 0;
        s += L[j];
    }
    int lane = t & 63, w = t >> 6;
    int incl = s;
    for (int o = 1; o < 64; o <<= 1) {
        int v = __shfl_up(incl, o);
        if (lane >= o) incl += v;
    }
    __shared__ int wsum[4];
    if (lane == 63) wsum[w] = incl;
    __syncthreads();
    int wbase = 0;
#pragma unroll
    for (int i = 0; i < 4; ++i) if (i < w) wbase += wsum[i];
    int run = bsums[blockIdx.x] + wbase + incl - s;
#pragma unroll
    for (int j = 0; j < 4; ++j) {
        int i = base + j;
        if (i <= NN) off[i] = run;
        if (i < NN)  cursor[i] = run;
        run += L[j];
    }
}

// ---------------------------------------------------------------------------
// Kernel: scatter edges into CSR slots (src id + edge_attr), by dst.
// ---------------------------------------------------------------------------
__global__ __launch_bounds__(256) void scatter_kernel(const int* __restrict__ ei,
                                                      const float* __restrict__ ea,
                                                      int* __restrict__ cursor,
                                                      int* __restrict__ esrc,
                                                      float* __restrict__ eattr)
{
    int e = blockIdx.x * blockDim.x + threadIdx.x;
    if (e >= EE) return;
    int d = ei[EE + e];
    int pos = atomicAdd(&cursor[d], 1);
    esrc[pos]  = ei[e];
    eattr[pos] = ea[e];
}

// ---------------------------------------------------------------------------
// Kernel: per-destination-node attention. One wave per node; lane = h*8+d.
// ---------------------------------------------------------------------------
__global__ __launch_bounds__(256) void attn_kernel(
    const float* __restrict__ Q, const float* __restrict__ K,
    const float* __restrict__ V,
    const int* __restrict__ off, const int* __restrict__ esrc,
    const float* __restrict__ eattr,
    const float* __restrict__ We, const float* __restrict__ be,
    float* __restrict__ out)
{
    const int lane = threadIdx.x & 63;
    const int node = blockIdx.x * 4 + (threadIdx.x >> 6);
    if (node >= NN) return;

    const float we  = We[lane];
    const float beL = be[lane];
    const float q   = Q[node * D64 + lane];

    const int i0 = off[node];
    const int i1 = off[node + 1];

    float acc = 0.f, z = 0.f;
    const float rs = 0.35355339059327373f;  // 1/sqrt(8)

    for (int i = i0; i < i1; ++i) {
        int   s = esrc[i];
        float a = eattr[i];
        float k = K[s * D64 + lane];
        float v = V[s * D64 + lane];
        float eh = fmaf(a, we, beL);
        float t  = k * q * eh;
        t += __shfl_xor(t, 1);
        t += __shfl_xor(t, 2);
        t += __shfl_xor(t, 4);
        t *= rs;
        t = fminf(fmaxf(t, -5.f), 5.f);
        float sc = __expf(t);
        acc = fmaf(v, sc, acc);
        z  += sc;
    }
    out[node * D64 + lane] = acc / (z + 1e-6f);
}

// ---------------------------------------------------------------------------
// Host launcher
// ---------------------------------------------------------------------------
static inline size_t align256(size_t v) { return (v + 255) & ~(size_t)255; }

extern "C" void kernel_launch(void* const* d_in, const int* in_sizes, int n_in,
                              void* d_out, int out_size, void* d_ws, size_t ws_size,
                              hipStream_t stream)
{
    const float* x  = (const float*)d_in[0];
    const float* ea = (const float*)d_in[1];
    const int*   ei = (const int*)  d_in[2];   // [2][EE]: row0=src, row1=dst
    const float* Wq = (const float*)d_in[3];
    const float* bq = (const float*)d_in[4];
    const float* Wk = (const float*)d_in[5];
    const float* bk = (const float*)d_in[6];
    const float* We = (const float*)d_in[7];
    const float* be = (const float*)d_in[8];
    const float* Wv = (const float*)d_in[9];
    const float* bv = (const float*)d_in[10];
    float* out = (float*)d_out;

    char* ws = (char*)d_ws;
    size_t o = 0;
    float* Q      = (float*)(ws + o); o += align256((size_t)NN * D64 * 4);
    float* K      = (float*)(ws + o); o += align256((size_t)NN * D64 * 4);
    float* V      = (float*)(ws + o); o += align256((size_t)NN * D64 * 4);
    int*   deg    = (int*)  (ws + o); o += align256((size_t)NN * 4);
    int*   cursor = (int*)  (ws + o); o += align256((size_t)NN * 4);
    int*   off    = (int*)  (ws + o); o += align256((size_t)(NN + 1) * 4);
    int*   bsums  = (int*)  (ws + o); o += align256(128 * 4);
    int*   esrc   = (int*)  (ws + o); o += align256((size_t)EE * 4);
    float* eattr  = (float*)(ws + o); o += align256((size_t)EE * 4);
    (void)ws_size; (void)out_size; (void)in_sizes; (void)n_in;

    const int nbScan = (NN + 1 + 1023) / 1024;   // 98

    hipMemsetAsync(deg, 0, (size_t)NN * 4, stream);

    qkv_kernel<<<(NN + 63) / 64, 256, 0, stream>>>(x, Wq, bq, Wk, bk, Wv, bv, Q, K, V);
    count_kernel<<<EE / 256, 256, 0, stream>>>(ei, deg);
    scanA_kernel<<<nbScan, 256, 0, stream>>>(deg, bsums);
    scanB_kernel<<<1, 128, 0, stream>>>(bsums, nbScan);
    scanC_kernel<<<nbScan, 256, 0, stream>>>(deg, bsums, off, cursor);
    scatter_kernel<<<EE / 256, 256, 0, stream>>>(ei, ea, cursor, esrc, eattr);
    attn_kernel<<<(NN + 3) / 4, 256, 0, stream>>>(Q, K, V, off, esrc, eattr, We, be, out);
}

// Round 3
// 420.887 us; speedup vs baseline: 1.4387x; 1.1923x over previous
//
#include <hip/hip_runtime.h>
#include <math.h>

#define NN 100000
#define EE 1600000
#define IND 128
#define D64 64   // HEADS*OUT_DIM

// ---------------------------------------------------------------------------
// Kernel 1: fused Q/K/V projection as one register-tiled LDS GEMM.
// C[100000 x 192] = x[100000 x 128] @ [Wq|Wk|Wv][128 x 192]
// Block: 256 threads, BM=64 nodes, BN=192 cols, BK=32.
// Thread tile: 8 nodes x 6 cols.
// ---------------------------------------------------------------------------
#define XS_STRIDE 36
#define WS_STRIDE 196

__global__ __launch_bounds__(256) void qkv_kernel(
    const float* __restrict__ x,
    const float* __restrict__ Wq, const float* __restrict__ bq,
    const float* __restrict__ Wk, const float* __restrict__ bk,
    const float* __restrict__ Wv, const float* __restrict__ bv,
    float* __restrict__ Qo, float* __restrict__ Ko, float* __restrict__ Vo)
{
    __shared__ float xs[64 * XS_STRIDE];   // [node][k]
    __shared__ float ws[32 * WS_STRIDE];   // [k][col]

    const int t    = threadIdx.x;
    const int tidn = t & 31;
    const int tidm = t >> 5;
    const int nb   = blockIdx.x * 64;

    float acc[6][8];
#pragma unroll
    for (int j = 0; j < 6; ++j)
#pragma unroll
        for (int n = 0; n < 8; ++n) acc[j][n] = 0.f;

    const float* const Wm[3] = { Wq, Wk, Wv };

    for (int kt = 0; kt < 4; ++kt) {
#pragma unroll
        for (int i = 0; i < 2; ++i) {
            int idx  = i * 256 + t;
            int node = idx >> 3, k4 = idx & 7;
            float4 v = make_float4(0.f, 0.f, 0.f, 0.f);
            if (nb + node < NN)
                v = *(const float4*)&x[(size_t)(nb + node) * IND + kt * 32 + k4 * 4];
            *(float4*)&xs[node * XS_STRIDE + k4 * 4] = v;
        }
#pragma unroll
        for (int m = 0; m < 3; ++m) {
#pragma unroll
            for (int i = 0; i < 2; ++i) {
                int idx = i * 256 + t;
                int k = idx >> 4, c4 = idx & 15;
                float4 v = *(const float4*)&Wm[m][(size_t)(kt * 32 + k) * D64 + c4 * 4];
                *(float4*)&ws[k * WS_STRIDE + m * 64 + c4 * 4] = v;
            }
        }
        __syncthreads();

#pragma unroll
        for (int k4 = 0; k4 < 8; ++k4) {
            float4 xv[8];
#pragma unroll
            for (int n = 0; n < 8; ++n)
                xv[n] = *(const float4*)&xs[(tidm * 8 + n) * XS_STRIDE + k4 * 4];
#pragma unroll
            for (int kk = 0; kk < 4; ++kk) {
                float wv[6];
#pragma unroll
                for (int j = 0; j < 6; ++j)
                    wv[j] = ws[(k4 * 4 + kk) * WS_STRIDE + j * 32 + tidn];
#pragma unroll
                for (int j = 0; j < 6; ++j) {
#pragma unroll
                    for (int n = 0; n < 8; ++n) {
                        float xe = (kk == 0) ? xv[n].x : (kk == 1) ? xv[n].y
                                 : (kk == 2) ? xv[n].z : xv[n].w;
                        acc[j][n] = fmaf(xe, wv[j], acc[j][n]);
                    }
                }
            }
        }
        __syncthreads();
    }

#pragma unroll
    for (int j = 0; j < 6; ++j) {
        int col = j * 32 + tidn;
        int m   = col >> 6, lc = col & 63;
        const float* bp = (m == 0) ? bq : (m == 1) ? bk : bv;
        float*       O  = (m == 0) ? Qo : (m == 1) ? Ko : Vo;
        float bias = bp[lc];
#pragma unroll
        for (int n = 0; n < 8; ++n) {
            int node = nb + tidm * 8 + n;
            if (node < NN)
                O[(size_t)node * D64 + lc] = acc[j][n] + bias;
        }
    }
}

// ---------------------------------------------------------------------------
// Kernel 2: degree count by destination node.
// ---------------------------------------------------------------------------
__global__ __launch_bounds__(256) void count_kernel(const int* __restrict__ ei,
                                                    int* __restrict__ deg)
{
    int e = blockIdx.x * blockDim.x + threadIdx.x;
    if (e < EE) atomicAdd(&deg[ei[EE + e]], 1);
}

// ---------------------------------------------------------------------------
// Exclusive prefix-sum over deg -> off[0..NN]; 3-kernel scan.
// ---------------------------------------------------------------------------
__global__ __launch_bounds__(256) void scanA_kernel(const int* __restrict__ deg,
                                                    int* __restrict__ bsums)
{
    int base = blockIdx.x * 1024 + threadIdx.x * 4;
    int s = 0;
#pragma unroll
    for (int j = 0; j < 4; ++j) {
        int i = base + j;
        s += (i < NN) ? deg[i] : 0;
    }
    for (int o = 32; o > 0; o >>= 1) s += __shfl_xor(s, o);
    __shared__ int ws[4];
    if ((threadIdx.x & 63) == 0) ws[threadIdx.x >> 6] = s;
    __syncthreads();
    if (threadIdx.x == 0) bsums[blockIdx.x] = ws[0] + ws[1] + ws[2] + ws[3];
}

__global__ __launch_bounds__(128) void scanB_kernel(int* __restrict__ bsums, int nb)
{
    __shared__ int sh[128];
    int t = threadIdx.x;
    int v = (t < nb) ? bsums[t] : 0;
    sh[t] = v;
    __syncthreads();
    for (int o = 1; o < 128; o <<= 1) {
        int add = (t >= o) ? sh[t - o] : 0;
        __syncthreads();
        sh[t] += add;
        __syncthreads();
    }
    if (t < nb) bsums[t] = sh[t] - v;   // exclusive
}

__global__ __launch_bounds__(256) void scanC_kernel(const int* __restrict__ deg,
                                                    const int* __restrict__ bsums,
                                                    int* __restrict__ off,
                                                    int* __restrict__ cursor)
{
    int t = threadIdx.x;
    int base = blockIdx.x * 1024 + t * 4;
    int L[4]; int s = 0;
#pragma unroll
    for (int j = 0; j < 4; ++j) {
        int i = base + j;
        L[j] = (i < NN) ? deg[i] : 0;
        s += L[j];
    }
    int lane = t & 63, w = t >> 6;
    int incl = s;
    for (int o = 1; o < 64; o <<= 1) {
        int v = __shfl_up(incl, o);
        if (lane >= o) incl += v;
    }
    __shared__ int wsum[4];
    if (lane == 63) wsum[w] = incl;
    __syncthreads();
    int wbase = 0;
#pragma unroll
    for (int i = 0; i < 4; ++i) if (i < w) wbase += wsum[i];
    int run = bsums[blockIdx.x] + wbase + incl - s;
#pragma unroll
    for (int j = 0; j < 4; ++j) {
        int i = base + j;
        if (i <= NN) off[i] = run;
        if (i < NN)  cursor[i] = run;
        run += L[j];
    }
}

// ---------------------------------------------------------------------------
// Kernel: scatter edges into CSR slots; packed (src, attr-bits) int2 record.
// ---------------------------------------------------------------------------
__global__ __launch_bounds__(256) void scatter_kernel(const int* __restrict__ ei,
                                                      const float* __restrict__ ea,
                                                      int* __restrict__ cursor,
                                                      int2* __restrict__ epack)
{
    int e = blockIdx.x * blockDim.x + threadIdx.x;
    if (e >= EE) return;
    int d = ei[EE + e];
    int pos = atomicAdd(&cursor[d], 1);
    epack[pos] = make_int2(ei[e], __float_as_int(ea[e]));
}

// ---------------------------------------------------------------------------
// Kernel: per-destination-node attention. One wave per node; lane = h*8+d.
// Edge loop unrolled x4: 4 edge records + 8 K/V gathers in flight per step.
// ---------------------------------------------------------------------------
__global__ __launch_bounds__(256) void attn_kernel(
    const float* __restrict__ Q, const float* __restrict__ K,
    const float* __restrict__ V,
    const int* __restrict__ off, const int2* __restrict__ epack,
    const float* __restrict__ We, const float* __restrict__ be,
    float* __restrict__ out)
{
    const int lane = threadIdx.x & 63;
    const int node = blockIdx.x * 4 + (threadIdx.x >> 6);
    if (node >= NN) return;

    const float we  = We[lane];
    const float beL = be[lane];
    // fold 1/sqrt(8) into q
    const float q   = Q[node * D64 + lane] * 0.35355339059327373f;

    const int i0 = off[node];
    const int i1 = off[node + 1];

    float acc = 0.f, z = 0.f;

    int i = i0;
    for (; i + 4 <= i1; i += 4) {
        int2 e0 = epack[i];
        int2 e1 = epack[i + 1];
        int2 e2 = epack[i + 2];
        int2 e3 = epack[i + 3];

        float k0 = K[(size_t)e0.x * D64 + lane];
        float k1 = K[(size_t)e1.x * D64 + lane];
        float k2 = K[(size_t)e2.x * D64 + lane];
        float k3 = K[(size_t)e3.x * D64 + lane];
        float v0 = V[(size_t)e0.x * D64 + lane];
        float v1 = V[(size_t)e1.x * D64 + lane];
        float v2 = V[(size_t)e2.x * D64 + lane];
        float v3 = V[(size_t)e3.x * D64 + lane];

        float t0 = k0 * q * fmaf(__int_as_float(e0.y), we, beL);
        float t1 = k1 * q * fmaf(__int_as_float(e1.y), we, beL);
        float t2 = k2 * q * fmaf(__int_as_float(e2.y), we, beL);
        float t3 = k3 * q * fmaf(__int_as_float(e3.y), we, beL);

        t0 += __shfl_xor(t0, 1); t1 += __shfl_xor(t1, 1);
        t2 += __shfl_xor(t2, 1); t3 += __shfl_xor(t3, 1);
        t0 += __shfl_xor(t0, 2); t1 += __shfl_xor(t1, 2);
        t2 += __shfl_xor(t2, 2); t3 += __shfl_xor(t3, 2);
        t0 += __shfl_xor(t0, 4); t1 += __shfl_xor(t1, 4);
        t2 += __shfl_xor(t2, 4); t3 += __shfl_xor(t3, 4);

        t0 = fminf(fmaxf(t0, -5.f), 5.f);
        t1 = fminf(fmaxf(t1, -5.f), 5.f);
        t2 = fminf(fmaxf(t2, -5.f), 5.f);
        t3 = fminf(fmaxf(t3, -5.f), 5.f);

        float s0 = __expf(t0), s1 = __expf(t1), s2 = __expf(t2), s3 = __expf(t3);
        acc = fmaf(v0, s0, acc); z += s0;
        acc = fmaf(v1, s1, acc); z += s1;
        acc = fmaf(v2, s2, acc); z += s2;
        acc = fmaf(v3, s3, acc); z += s3;
    }
    for (; i < i1; ++i) {
        int2 e = epack[i];
        float k = K[(size_t)e.x * D64 + lane];
        float v = V[(size_t)e.x * D64 + lane];
        float t = k * q * fmaf(__int_as_float(e.y), we, beL);
        t += __shfl_xor(t, 1);
        t += __shfl_xor(t, 2);
        t += __shfl_xor(t, 4);
        t = fminf(fmaxf(t, -5.f), 5.f);
        float sc = __expf(t);
        acc = fmaf(v, sc, acc);
        z  += sc;
    }
    out[node * D64 + lane] = acc / (z + 1e-6f);
}

// ---------------------------------------------------------------------------
// Host launcher
// ---------------------------------------------------------------------------
static inline size_t align256(size_t v) { return (v + 255) & ~(size_t)255; }

extern "C" void kernel_launch(void* const* d_in, const int* in_sizes, int n_in,
                              void* d_out, int out_size, void* d_ws, size_t ws_size,
                              hipStream_t stream)
{
    const float* x  = (const float*)d_in[0];
    const float* ea = (const float*)d_in[1];
    const int*   ei = (const int*)  d_in[2];   // [2][EE]: row0=src, row1=dst
    const float* Wq = (const float*)d_in[3];
    const float* bq = (const float*)d_in[4];
    const float* Wk = (const float*)d_in[5];
    const float* bk = (const float*)d_in[6];
    const float* We = (const float*)d_in[7];
    const float* be = (const float*)d_in[8];
    const float* Wv = (const float*)d_in[9];
    const float* bv = (const float*)d_in[10];
    float* out = (float*)d_out;

    char* ws = (char*)d_ws;
    size_t o = 0;
    float* Q      = (float*)(ws + o); o += align256((size_t)NN * D64 * 4);
    float* K      = (float*)(ws + o); o += align256((size_t)NN * D64 * 4);
    float* V      = (float*)(ws + o); o += align256((size_t)NN * D64 * 4);
    int*   deg    = (int*)  (ws + o); o += align256((size_t)NN * 4);
    int*   cursor = (int*)  (ws + o); o += align256((size_t)NN * 4);
    int*   off    = (int*)  (ws + o); o += align256((size_t)(NN + 1) * 4);
    int*   bsums  = (int*)  (ws + o); o += align256(128 * 4);
    int2*  epack  = (int2*) (ws + o); o += align256((size_t)EE * 8);
    (void)ws_size; (void)out_size; (void)in_sizes; (void)n_in;

    const int nbScan = (NN + 1 + 1023) / 1024;   // 98

    hipMemsetAsync(deg, 0, (size_t)NN * 4, stream);

    qkv_kernel<<<(NN + 63) / 64, 256, 0, stream>>>(x, Wq, bq, Wk, bk, Wv, bv, Q, K, V);
    count_kernel<<<EE / 256, 256, 0, stream>>>(ei, deg);
    scanA_kernel<<<nbScan, 256, 0, stream>>>(deg, bsums);
    scanB_kernel<<<1, 128, 0, stream>>>(bsums, nbScan);
    scanC_kernel<<<nbScan, 256, 0, stream>>>(deg, bsums, off, cursor);
    scatter_kernel<<<EE / 256, 256, 0, stream>>>(ei, ea, cursor, epack);
    attn_kernel<<<(NN + 3) / 4, 256, 0, stream>>>(Q, K, V, off, epack, We, be, out);
}